// Round 5
// baseline (534.633 us; speedup 1.0000x reference)
//
#include <hip/hip_runtime.h>

typedef __bf16 bf16x8 __attribute__((ext_vector_type(8)));
typedef float  f32x4  __attribute__((ext_vector_type(4)));
typedef unsigned short u16;
typedef u16 u16x8 __attribute__((ext_vector_type(8)));

__device__ __forceinline__ bf16x8 packA(f32x4 a0, f32x4 a1) {
    bf16x8 r;
    r[0] = (__bf16)a0[0]; r[1] = (__bf16)a0[1]; r[2] = (__bf16)a0[2]; r[3] = (__bf16)a0[3];
    r[4] = (__bf16)a1[0]; r[5] = (__bf16)a1[1]; r[6] = (__bf16)a1[2]; r[7] = (__bf16)a1[3];
    return r;
}

// ---------------------------------------------------------------------------
// Gather + fp32->bf16 + FRAGMENT-PACK for the GEMM's B operand.
// BP[((s*8 + cf)*64 + lhi*16 + l15) * 8 + e] = B[n = cf*16+l15][k = s*32+lhi*8+e]
// A GEMM wave's B-load is 64 lanes x 16B CONTIGUOUS (1KB). Zero-pads k>=Kcnt.
// ---------------------------------------------------------------------------
__global__ __launch_bounds__(256) void gather_bt(
    const float* __restrict__ feats, const int* __restrict__ idx,
    u16* __restrict__ BP, int Kcnt)
{
    __shared__ u16 st[128][72];
    const int tid = threadIdx.x;
    const int k0  = blockIdx.x * 64;

#pragma unroll
    for (int r2 = 0; r2 < 64; r2 += 2) {
        int r = r2 + (tid >> 7);         // k_local
        int c = tid & 127;               // feature n
        int k = k0 + r;
        float v = 0.f;
        if (k < Kcnt) v = feats[(size_t)idx[k] * 128 + c];
        st[c][r] = __builtin_bit_cast(u16, (__bf16)v);
    }
    __syncthreads();

    const int s_local = tid >> 7;        // 0..1
    const int cf      = (tid >> 4) & 7;
    const int l15     = tid & 15;
    const int s       = blockIdx.x * 2 + s_local;
    const int n       = cf * 16 + l15;
#pragma unroll
    for (int lhi = 0; lhi < 4; ++lhi) {
        u16x8 v = *(const u16x8*)&st[n][s_local * 32 + lhi * 8];
        *(u16x8*)(BP + ((size_t)(s * 8 + cf) * 64 + lhi * 16 + l15) * 8) = v;
    }
}

// ---------------------------------------------------------------------------
// Split-K GEMM, NO ATOMICS: P[split][M][128] = A[M][K](f32) * B (bf16 BP).
// Block = 4 waves = 64 rows; wave = 16 rows x 128 cols (16x16x32 MFMA).
// Macro = 128 k (4 ksteps). A staged global->LDS via global_load_lds (1KB
// line-sequential per instr), double-buffered, source-side XOR swizzle so
// fragment ds_read_b128s are bank-spread. B register-pipelined one kstep
// ahead. One barrier per macro. Plain-store epilogue into this split's slice.
// ---------------------------------------------------------------------------
__global__ __launch_bounds__(256, 2) void gemm_bt(
    const float* __restrict__ A, const u16* __restrict__ BP,
    float* __restrict__ P, int M, int K, int nmacro, int mspan, int nktot)
{
    __shared__ float As[2][64][128];     // 64KB
    const int tid  = threadIdx.x;
    const int wid  = tid >> 6;
    const int lane = tid & 63;
    const int l15  = lane & 15;
    const int lhi  = lane >> 4;
    const int swz  = l15 & 7;
    const int row0 = blockIdx.x * 64 + wid * 16;

    float* __restrict__ Pslice = P + (size_t)blockIdx.y * M * 128;

    int m0 = blockIdx.y * mspan;
    int m1 = m0 + mspan; if (m1 > nmacro) m1 = nmacro;
    if (m0 >= m1) {                      // insurance: empty split -> zeros
#pragma unroll
        for (int cf = 0; cf < 8; ++cf)
#pragma unroll
            for (int i = 0; i < 4; ++i) {
                const int r = row0 + lhi * 4 + i;
                if (r < M) Pslice[(size_t)r * 128 + cf * 16 + l15] = 0.f;
            }
        return;
    }

    auto stage = [&](int m, int buf) {
        const int kbase = m << 7;
        if (kbase + 128 <= K) {          // fast path: async 1KB line-sequential
#pragma unroll
            for (int i = 0; i < 8; ++i) {
                const int lr = wid * 16 + i * 2 + (lane >> 5);       // local row
                const int ar = min(blockIdx.x * 64 + lr, M - 1);
                const float* src = A + (size_t)ar * K + kbase
                                 + (((lane & 31) ^ (lr & 7)) << 2);  // swizzled source
                __builtin_amdgcn_global_load_lds(
                    (const __attribute__((address_space(1))) void*)src,
                    (__attribute__((address_space(3))) void*)&As[buf][wid * 16 + i * 2][0],
                    16, 0, 0);
            }
        } else {                          // tail macro (hop-1 only): guarded reg-stage
#pragma unroll
            for (int i = 0; i < 8; ++i) {
                const int lr = wid * 16 + i * 2 + (lane >> 5);
                const int ar = min(blockIdx.x * 64 + lr, M - 1);
                const int u  = lane & 31;
                const float* src = A + (size_t)ar * K + kbase + (u << 2);
                f32x4 v;
#pragma unroll
                for (int e = 0; e < 4; ++e) {
                    int kk = kbase + (u << 2) + e;
                    v[e] = (kk < K) ? src[e] : 0.f;
                }
                *(f32x4*)&As[buf][lr][(u ^ (lr & 7)) << 2] = v;
            }
        }
    };

    stage(m0, 0);

    f32x4 acc[8];
#pragma unroll
    for (int j = 0; j < 8; ++j) acc[j] = (f32x4){0.f, 0.f, 0.f, 0.f};

    const u16* __restrict__ bp_lane = BP + (size_t)lane * 8;

    bf16x8 bcur[8];
    {
        const int s_first = m0 << 2;
#pragma unroll
        for (int cf = 0; cf < 8; ++cf)
            bcur[cf] = __builtin_bit_cast(bf16x8,
                *(const u16x8*)(bp_lane + ((size_t)(s_first * 8 + cf) << 9)));
    }

    __builtin_amdgcn_s_waitcnt(0x0F70);  // vmcnt(0): gload_lds landed
    __syncthreads();

    for (int m = m0; m < m1; ++m) {
        const int buf = (m - m0) & 1;
        if (m + 1 < m1) stage(m + 1, buf ^ 1);

#pragma unroll
        for (int j = 0; j < 4; ++j) {
            const int s  = (m << 2) + j;
            int sn = s + 1; if (sn > nktot - 1) sn = nktot - 1;   // clamp (unused past end)
            bf16x8 bnxt[8];
#pragma unroll
            for (int cf = 0; cf < 8; ++cf)
                bnxt[cf] = __builtin_bit_cast(bf16x8,
                    *(const u16x8*)(bp_lane + ((size_t)(sn * 8 + cf) << 9)));

            const int ub = (j << 3) + (lhi << 1);                  // fp32 16B-unit
            const f32x4 a0 = *(const f32x4*)&As[buf][wid * 16 + l15][(ub ^ swz) << 2];
            const f32x4 a1 = *(const f32x4*)&As[buf][wid * 16 + l15][((ub + 1) ^ swz) << 2];
            const bf16x8 af = packA(a0, a1);

#pragma unroll
            for (int cf = 0; cf < 8; ++cf)
                acc[cf] = __builtin_amdgcn_mfma_f32_16x16x32_bf16(af, bcur[cf], acc[cf], 0, 0, 0);

#pragma unroll
            for (int cf = 0; cf < 8; ++cf) bcur[cf] = bnxt[cf];
        }

        __builtin_amdgcn_s_waitcnt(0x0F70);  // vmcnt(0): next-buf stage landed
        __syncthreads();
    }

    // Plain-store epilogue: C/D layout col = lane&15, row = (lane>>4)*4 + i
#pragma unroll
    for (int cf = 0; cf < 8; ++cf)
#pragma unroll
        for (int i = 0; i < 4; ++i) {
            const int r = row0 + lhi * 4 + i;
            if (r < M)
                Pslice[(size_t)r * 128 + cf * 16 + l15] = acc[cf][i];
        }
}

// ---------------------------------------------------------------------------
// out[M][128] = relu(concat(sum_s P[s][m][:], fsrc[didx[m]][:]) @ w[256][128])
// Fused split-K reduce + concat + dense + relu.
// ---------------------------------------------------------------------------
__global__ __launch_bounds__(256) void dense_relu(
    const float* __restrict__ P, int nsplit,
    const float* __restrict__ fsrc, const int* __restrict__ didx,
    const float* __restrict__ w, float* __restrict__ out, int M)
{
    __shared__ float sb[32][257];
    const int tid  = threadIdx.x;
    const int row0 = blockIdx.x * 32;

    for (int i = tid; i < 32 * 32; i += 256) {           // reduced-agg half
        int r = i >> 5, c4 = (i & 31) << 2;
        int gr = row0 + r;
        f32x4 v = (f32x4){0.f, 0.f, 0.f, 0.f};
        if (gr < M)
            for (int s = 0; s < nsplit; ++s)
                v += *(const f32x4*)(P + ((size_t)s * M + gr) * 128 + c4);
        sb[r][c4 + 0] = v[0]; sb[r][c4 + 1] = v[1];
        sb[r][c4 + 2] = v[2]; sb[r][c4 + 3] = v[3];
    }
    for (int i = tid; i < 32 * 32; i += 256) {           // gathered dst half
        int r = i >> 5, c4 = (i & 31) << 2;
        int gr = row0 + r;
        int sr = (gr < M) ? didx[gr] : 0;
        f32x4 v = *(const f32x4*)(fsrc + (size_t)sr * 128 + c4);
        sb[r][128 + c4 + 0] = v[0]; sb[r][128 + c4 + 1] = v[1];
        sb[r][128 + c4 + 2] = v[2]; sb[r][128 + c4 + 3] = v[3];
    }
    __syncthreads();

    const int colg = (tid & 15) << 3;
    const int r0l  = (tid >> 4) * 2;
    float acc0[8], acc1[8];
#pragma unroll
    for (int c = 0; c < 8; ++c) { acc0[c] = 0.f; acc1[c] = 0.f; }

#pragma unroll 4
    for (int j = 0; j < 256; ++j) {
        f32x4 wa = *(const f32x4*)(w + j * 128 + colg);
        f32x4 wb = *(const f32x4*)(w + j * 128 + colg + 4);
        float a0 = sb[r0l][j];
        float a1 = sb[r0l + 1][j];
#pragma unroll
        for (int c = 0; c < 4; ++c) {
            acc0[c]     += a0 * wa[c];  acc0[c + 4] += a0 * wb[c];
            acc1[c]     += a1 * wa[c];  acc1[c + 4] += a1 * wb[c];
        }
    }

    int gr0 = row0 + r0l;
    if (gr0 < M) {
#pragma unroll
        for (int c = 0; c < 8; ++c)
            out[(size_t)gr0 * 128 + colg + c] = fmaxf(acc0[c], 0.f);
    }
    int gr1 = gr0 + 1;
    if (gr1 < M) {
#pragma unroll
        for (int c = 0; c < 8; ++c)
            out[(size_t)gr1 * 128 + colg + c] = fmaxf(acc1[c], 0.f);
    }
}

// ---------------------------------------------------------------------------
extern "C" void kernel_launch(void* const* d_in, const int* in_sizes, int n_in,
                              void* d_out, int out_size, void* d_ws, size_t ws_size,
                              hipStream_t stream)
{
    const float* src_nodes = (const float*)d_in[0];
    const int*   s1idx     = (const int*)d_in[1];
    const int*   s2idx     = (const int*)d_in[2];
    const int*   d1idx     = (const int*)d_in[3];
    const int*   d2idx     = (const int*)d_in[4];
    const float* dif1      = (const float*)d_in[5];
    const float* dif2      = (const float*)d_in[6];
    const float* w1        = (const float*)d_in[7];
    const float* w2        = (const float*)d_in[8];
    float*       out       = (float*)d_out;

    const int M2 = 4000, M1 = 1024;
    const int K2 = 16000, K1 = 3500;
    const int NK2 = 500, NK1 = 112;      // kstep counts (k/32), BP zero-padded
    const int KS2 = 8,   KS1 = 14;       // k-splits

    char* ws = (char*)d_ws;
    size_t off = 0;
    float* P2  = (float*)(ws + off); off += (size_t)KS2 * M2 * 128 * 4;  // 16.38 MB
    float* P1  = (float*)(ws + off); off += (size_t)KS1 * M1 * 128 * 4;  //  7.34 MB
    float* x   = (float*)(ws + off); off += (size_t)M2 * 128 * 4;        //  2.05 MB
    u16*   BP2 = (u16*)(ws + off);   off += (size_t)NK2 * 8 * 64 * 8 * 2;//  4.10 MB
    u16*   BP1 = (u16*)(ws + off);   off += (size_t)NK1 * 8 * 64 * 8 * 2;//  0.92 MB

    // ---- hop 2 ----
    gather_bt<<<NK2 / 2, 256, 0, stream>>>(src_nodes, s2idx, BP2, K2);
    {
        // 125 macros; ksplit=8, mspan=16 (last split 13); grid 63x8
        dim3 grid((M2 + 63) / 64, KS2);
        gemm_bt<<<grid, 256, 0, stream>>>(dif2, BP2, P2, M2, K2, 125, 16, NK2);
    }
    dense_relu<<<(M2 + 31) / 32, 256, 0, stream>>>(P2, KS2, src_nodes, d2idx, w1, x, M2);

    // ---- hop 1 ----
    gather_bt<<<NK1 / 2, 256, 0, stream>>>(x, s1idx, BP1, K1);
    {
        // 28 macros; ksplit=14, mspan=2; grid 16x14
        dim3 grid((M1 + 63) / 64, KS1);
        gemm_bt<<<grid, 256, 0, stream>>>(dif1, BP1, P1, M1, K1, 28, 2, NK1);
    }
    dense_relu<<<(M1 + 31) / 32, 256, 0, stream>>>(P1, KS1, x, d1idx, w2, out, M1);
}